// Round 8
// baseline (269.496 us; speedup 1.0000x reference)
//
#include <hip/hip_runtime.h>

#define H 256
#define W 256
#define BATCH 8
#define CIN 16
#define TW 32
#define TH 4
#define HWC (TW + 2)        // 34 halo cols
#define HHC (TH + 2)        // 6 halo rows
#define NHALO (HWC * HHC)   // 204 halo pixels
#define HSTR 20             // shorts per halo pixel (16 data + 4 pad) -> 40B stride, bank-clean b64
#define NPIX_TOTAL (BATCH * H * W)   // 524288
#define GAP_TAU 8e-3f

typedef __attribute__((ext_vector_type(8))) short short8;       // 8 fp16 bit-patterns
typedef __attribute__((ext_vector_type(8))) _Float16 half8;     // MFMA A/B frag
typedef __attribute__((ext_vector_type(4))) float f32x4;        // MFMA C/D frag

union S8H8 { short8 s; half8 h; };
__device__ __forceinline__ half8 as_h8(short8 s) { S8H8 u; u.s = s; return u.h; }
union HU { _Float16 h; unsigned short u; };
__device__ __forceinline__ unsigned short f2h_bits(float f) { HU u; u.h = (_Float16)f; return u.u; }
union D2S8 { double d[2]; short8 s; };       // two b64 LDS reads -> one A-frag
union S4D  { unsigned short s[4]; double d; };

#define MFMA16(A, B, C) __builtin_amdgcn_mfma_f32_16x16x32_f16(as_h8(A), as_h8(B), C, 0, 0, 0)

// weight [oc][ic][3][3] fp32 ->
//   wt2 fp16 bits, x64-scaled, FRAGMENT layout [tap][ks][q][n=oc][j=8k] (36864 shorts)
//       so a wave's B-frag load is 4x256B contiguous segments (coalesced)
//   wT  fp32 exact, layout [tap][ic][oc] (fixup, lane-coalesced)       (36864 floats)
// also zeroes fix_cnt (replaces a memset dispatch)
__global__ void wprep_kernel(const float* __restrict__ w, unsigned short* __restrict__ wt2,
                             float* __restrict__ wT, unsigned* __restrict__ fix_cnt) {
    int i = blockIdx.x * 256 + threadIdx.x;   // 9*64*64 = 36864
    if (blockIdx.x == 0 && threadIdx.x < 4) fix_cnt[threadIdx.x] = 0u;
    if (i >= 36864) return;
    int ic  = i & 63;
    int oc  = (i >> 6) & 63;
    int tap = i >> 12;
    float v = w[(oc * 64 + ic) * 9 + tap];
    int ks = ic >> 5, qq = (ic >> 3) & 3, j = ic & 7;
    wt2[((((tap * 2 + ks) * 4 + qq) * 64) + oc) * 8 + j] = f2h_bits(v * 64.0f);
    wT[(tap * 64 + ic) * 64 + oc] = v;
}

// epilogue for one 16-pixel m-tile: in-register shuffle reduction, no LDS
#define EPILOGUE_TILE(ACC, MT)                                                 \
    _Pragma("unroll")                                                          \
    for (int r = 0; r < 4; ++r) {                                              \
        float v0 = ACC[0][r] * SH + bv0;                                       \
        float v1 = ACC[1][r] * SH + bv1;                                       \
        float v2 = ACC[2][r] * SH + bv2;                                       \
        float v3 = ACC[3][r] * SH + bv3;                                       \
        float m0 = v0, m1 = v1, m2 = v2, m3 = v3;                              \
        m0 = fmaxf(m0, __shfl_xor(m0, 1, 64));                                 \
        m0 = fmaxf(m0, __shfl_xor(m0, 2, 64));                                 \
        m0 = fmaxf(m0, __shfl_xor(m0, 4, 64));                                 \
        m0 = fmaxf(m0, __shfl_xor(m0, 8, 64));                                 \
        m1 = fmaxf(m1, __shfl_xor(m1, 1, 64));                                 \
        m1 = fmaxf(m1, __shfl_xor(m1, 2, 64));                                 \
        m1 = fmaxf(m1, __shfl_xor(m1, 4, 64));                                 \
        m1 = fmaxf(m1, __shfl_xor(m1, 8, 64));                                 \
        m2 = fmaxf(m2, __shfl_xor(m2, 1, 64));                                 \
        m2 = fmaxf(m2, __shfl_xor(m2, 2, 64));                                 \
        m2 = fmaxf(m2, __shfl_xor(m2, 4, 64));                                 \
        m2 = fmaxf(m2, __shfl_xor(m2, 8, 64));                                 \
        m3 = fmaxf(m3, __shfl_xor(m3, 1, 64));                                 \
        m3 = fmaxf(m3, __shfl_xor(m3, 2, 64));                                 \
        m3 = fmaxf(m3, __shfl_xor(m3, 4, 64));                                 \
        m3 = fmaxf(m3, __shfl_xor(m3, 8, 64));                                 \
        int bg = 0; float best = m0;                                           \
        if (m1 > best) { best = m1; bg = 1; }                                  \
        if (m2 > best) { best = m2; bg = 2; }                                  \
        if (m3 > best) { best = m3; bg = 3; }                                  \
        float sel = (bg == 0) ? v0 : (bg == 1) ? v1 : (bg == 2) ? v2 : v3;     \
        int gx = x0 + (MT) * 16 + q * 4 + r;                                   \
        size_t opix = pixrow + gx;                                             \
        out_sel[opix * 16 + lm] = sel;                                         \
        if (lm == 0) {                                                         \
            out_idx[opix] = (float)bg;                                         \
            float s1 = (bg == 0) ? m1 : m0;                                    \
            float s2 = (bg <= 1) ? m2 : m1;                                    \
            float s3 = (bg <= 2) ? m3 : m2;                                    \
            if (best - fmaxf(s1, fmaxf(s2, s3)) < GAP_TAU) {                   \
                unsigned slot = atomicAdd(fix_cnt, 1u);                        \
                if (slot < fix_cap) fix_list[slot] = (unsigned)opix;           \
            }                                                                  \
        }                                                                      \
    }

__global__ __launch_bounds__(256, 4) void ssconv_mfma_kernel(
    const float* __restrict__ x, const int* __restrict__ gidx,
    const unsigned short* __restrict__ wt2, const float* __restrict__ bias,
    float* __restrict__ out_sel, float* __restrict__ out_idx,
    unsigned* __restrict__ fix_cnt, unsigned* __restrict__ fix_list, unsigned fix_cap)
{
    __shared__ unsigned short hHi[NHALO * HSTR];          // 8160 B (x as fp16, padded)
    __shared__ int gsL[NHALO];                            // 816 B

    const int tid = threadIdx.x;
    const int x0 = blockIdx.x * TW;
    const int y0 = blockIdx.y * TH;
    const int bz = blockIdx.z;

    const int wvid = tid >> 6;        // wave id 0..3 -> tile row
    const int L    = tid & 63;
    const int q    = L >> 4;          // quad
    const int lm   = L & 15;
    const int gq   = q >> 1;          // ks=0 group base; ks=1 is gq+2
    const int c0s  = (q & 1) * 8;     // channel offset (shorts) within pixel

    // bias for this lane's 4 channels (n = nt*16 + lm) — loaded early
    const float bv0 = bias[lm];
    const float bv1 = bias[16 + lm];
    const float bv2 = bias[32 + lm];
    const float bv3 = bias[48 + lm];

    // ---- stage halo as fp16 + group map (the ONLY barrier in the kernel) ----
    if (tid < NHALO) {
        int r = tid / HWC, c = tid % HWC;
        int hy = y0 + r - 1, hx = x0 + c - 1;
        bool ok = (hy >= 0) && (hy < H) && (hx >= 0) && (hx < W);
        float4 a0 = make_float4(0, 0, 0, 0), a1 = a0, a2 = a0, a3 = a0;
        int g = 0;
        if (ok) {
            const float4* src = (const float4*)(x + (((size_t)bz * H + hy) * W + hx) * CIN);
            a0 = src[0]; a1 = src[1]; a2 = src[2]; a3 = src[3];
            g = gidx[((size_t)bz * H + hy) * W + hx];
        }
        gsL[tid] = g;
        S4D q0, q1, q2, q3;
        q0.s[0] = f2h_bits(a0.x); q0.s[1] = f2h_bits(a0.y);
        q0.s[2] = f2h_bits(a0.z); q0.s[3] = f2h_bits(a0.w);
        q1.s[0] = f2h_bits(a1.x); q1.s[1] = f2h_bits(a1.y);
        q1.s[2] = f2h_bits(a1.z); q1.s[3] = f2h_bits(a1.w);
        q2.s[0] = f2h_bits(a2.x); q2.s[1] = f2h_bits(a2.y);
        q2.s[2] = f2h_bits(a2.z); q2.s[3] = f2h_bits(a2.w);
        q3.s[0] = f2h_bits(a3.x); q3.s[1] = f2h_bits(a3.y);
        q3.s[2] = f2h_bits(a3.z); q3.s[3] = f2h_bits(a3.w);
        unsigned short* hp = hHi + tid * HSTR;
        *(double*)(hp + 0)  = q0.d;
        *(double*)(hp + 4)  = q1.d;
        *(double*)(hp + 8)  = q2.d;
        *(double*)(hp + 12) = q3.d;
    }
    __syncthreads();

    f32x4 acc0[4] = {}, acc1[4] = {};   // 2 m-tiles x 4 n-tiles, 16x16 each

    // lane-constant part of the B address: q*1024 + lm*16 bytes
    const char* wlane = (const char*)wt2 + (q << 10) + (lm << 4);

#pragma unroll 1
    for (int dy = 0; dy < 3; ++dy) {
        const int rb = (wvid + dy) * HWC + lm;
#pragma unroll
        for (int dx = 0; dx < 3; ++dx) {
            const int tap = dy * 3 + dx;
            const int p0 = rb + dx;          // m-tile 0 halo pixel
            const int p1 = p0 + 16;          // m-tile 1
            const int g0 = gsL[p0];
            const int g1 = gsL[p1];
            D2S8 ua0, ua1;
            ua0.d[0] = *(const double*)(hHi + p0 * HSTR + c0s);
            ua0.d[1] = *(const double*)(hHi + p0 * HSTR + c0s + 4);
            ua1.d[0] = *(const double*)(hHi + p1 * HSTR + c0s);
            ua1.d[1] = *(const double*)(hHi + p1 * HSTR + c0s + 4);

            const char* wk = wlane + tap * 8192;
            short8 b00 = *(const short8*)(wk + 0);
            short8 b01 = *(const short8*)(wk + 256);
            short8 b02 = *(const short8*)(wk + 512);
            short8 b03 = *(const short8*)(wk + 768);
            short8 b10 = *(const short8*)(wk + 4096);
            short8 b11 = *(const short8*)(wk + 4352);
            short8 b12 = *(const short8*)(wk + 4608);
            short8 b13 = *(const short8*)(wk + 4864);

            short8 z = (short8)0;
            short8 a00 = (g0 == gq)     ? ua0.s : z;   // ks=0 mask
            short8 a10 = (g1 == gq)     ? ua1.s : z;
            short8 a01 = (g0 == gq + 2) ? ua0.s : z;   // ks=1 mask
            short8 a11 = (g1 == gq + 2) ? ua1.s : z;

            acc0[0] = MFMA16(a00, b00, acc0[0]);
            acc0[1] = MFMA16(a00, b01, acc0[1]);
            acc0[2] = MFMA16(a00, b02, acc0[2]);
            acc0[3] = MFMA16(a00, b03, acc0[3]);
            acc1[0] = MFMA16(a10, b00, acc1[0]);
            acc1[1] = MFMA16(a10, b01, acc1[1]);
            acc1[2] = MFMA16(a10, b02, acc1[2]);
            acc1[3] = MFMA16(a10, b03, acc1[3]);
            acc0[0] = MFMA16(a01, b10, acc0[0]);
            acc0[1] = MFMA16(a01, b11, acc0[1]);
            acc0[2] = MFMA16(a01, b12, acc0[2]);
            acc0[3] = MFMA16(a01, b13, acc0[3]);
            acc1[0] = MFMA16(a11, b10, acc1[0]);
            acc1[1] = MFMA16(a11, b11, acc1[1]);
            acc1[2] = MFMA16(a11, b12, acc1[2]);
            acc1[3] = MFMA16(a11, b13, acc1[3]);
        }
    }

    // ---- epilogue: fully in-register, no LDS, no barriers ----
    const float SH = 0.015625f;          // 1/64 (weights pre-scaled x64)
    const size_t pixrow = ((size_t)bz * H + (y0 + wvid)) * W;

    EPILOGUE_TILE(acc0, 0)
    EPILOGUE_TILE(acc1, 1)
}

// fp64 exact recompute; one wave per pixel, lane = oc. Uses wT [tap][ic][oc]
// (lane-coalesced) and float4 x loads. If the flag list overflowed its cap,
// deterministically recompute ALL pixels (output never depends on atomic order).
__global__ void fixup_kernel(const float* __restrict__ x, const int* __restrict__ gidx,
                             const float* __restrict__ wT, const float* __restrict__ bias,
                             float* __restrict__ out_sel, float* __restrict__ out_idx,
                             const unsigned* __restrict__ fix_cnt,
                             const unsigned* __restrict__ fix_list, unsigned fix_cap)
{
    unsigned n = *fix_cnt;
    const bool full = (n > fix_cap);
    const unsigned total = full ? (unsigned)NPIX_TOTAL : n;
    const int lane = threadIdx.x & 63;
    const unsigned nwaves = gridDim.x * (blockDim.x >> 6);
    unsigned widx = blockIdx.x * (blockDim.x >> 6) + (threadIdx.x >> 6);

    for (; widx < total; widx += nwaves) {
        unsigned opix = full ? widx : fix_list[widx];
        int b  = opix >> 16;
        int y  = (opix >> 8) & 255;
        int xc = opix & 255;
        double acc = (double)bias[lane];
        for (int dy = 0; dy < 3; ++dy) {
            int yy = y + dy - 1;
            if (yy < 0 || yy >= H) continue;
            for (int dx = 0; dx < 3; ++dx) {
                int xx = xc + dx - 1;
                if (xx < 0 || xx >= W) continue;
                size_t pix = ((size_t)b * H + yy) * W + xx;
                int g = gidx[pix];
                const float4* xp = (const float4*)(x + pix * 16);
                float4 x0 = xp[0], x1 = xp[1], x2 = xp[2], x3 = xp[3];
                const float* wp = wT + (size_t)((dy * 3 + dx) * 64 + g * 16) * 64 + lane;
                acc = fma((double)wp[0 * 64],  (double)x0.x, acc);
                acc = fma((double)wp[1 * 64],  (double)x0.y, acc);
                acc = fma((double)wp[2 * 64],  (double)x0.z, acc);
                acc = fma((double)wp[3 * 64],  (double)x0.w, acc);
                acc = fma((double)wp[4 * 64],  (double)x1.x, acc);
                acc = fma((double)wp[5 * 64],  (double)x1.y, acc);
                acc = fma((double)wp[6 * 64],  (double)x1.z, acc);
                acc = fma((double)wp[7 * 64],  (double)x1.w, acc);
                acc = fma((double)wp[8 * 64],  (double)x2.x, acc);
                acc = fma((double)wp[9 * 64],  (double)x2.y, acc);
                acc = fma((double)wp[10 * 64], (double)x2.z, acc);
                acc = fma((double)wp[11 * 64], (double)x2.w, acc);
                acc = fma((double)wp[12 * 64], (double)x3.x, acc);
                acc = fma((double)wp[13 * 64], (double)x3.y, acc);
                acc = fma((double)wp[14 * 64], (double)x3.z, acc);
                acc = fma((double)wp[15 * 64], (double)x3.w, acc);
            }
        }
        double m = acc;
        m = fmax(m, __shfl_xor(m, 1, 64));
        m = fmax(m, __shfl_xor(m, 2, 64));
        m = fmax(m, __shfl_xor(m, 4, 64));
        m = fmax(m, __shfl_xor(m, 8, 64));
        double g0 = __shfl(m, 0, 64), g1 = __shfl(m, 16, 64);
        double g2 = __shfl(m, 32, 64), g3 = __shfl(m, 48, 64);
        int bg = 0; double bb = g0;
        if (g1 > bb) { bb = g1; bg = 1; }
        if (g2 > bb) { bb = g2; bg = 2; }
        if (g3 > bb) { bb = g3; bg = 3; }
        if ((lane >> 4) == bg) out_sel[(size_t)opix * 16 + (lane & 15)] = (float)acc;
        if (lane == 0) out_idx[opix] = (float)bg;
    }
}

extern "C" void kernel_launch(void* const* d_in, const int* in_sizes, int n_in,
                              void* d_out, int out_size, void* d_ws, size_t ws_size,
                              hipStream_t stream) {
    const float* x    = (const float*)d_in[0];
    const int*   gidx = (const int*)d_in[1];
    const float* w    = (const float*)d_in[2];
    const float* bias = (const float*)d_in[3];

    unsigned short* wt2 = (unsigned short*)d_ws;                    // 73728 B
    float* wT           = (float*)((char*)d_ws + 73728);            // 147456 B
    unsigned* fix_cnt   = (unsigned*)((char*)d_ws + 221184);        // 16 B
    unsigned* fix_list  = (unsigned*)((char*)d_ws + 221200);        // rest

    size_t avail = (ws_size > 221200) ? (ws_size - 221200) / 4 : 0;
    unsigned fix_cap = (unsigned)(avail < (size_t)NPIX_TOTAL ? avail : (size_t)NPIX_TOTAL);

    float* out_sel = (float*)d_out;                               // 8*256*256*16
    float* out_idx = (float*)d_out + (size_t)BATCH * H * W * CIN; // 8*256*256

    wprep_kernel<<<144, 256, 0, stream>>>(w, wt2, wT, fix_cnt);

    dim3 grid(W / TW, H / TH, BATCH);   // 8 x 64 x 8 = 4096 blocks
    ssconv_mfma_kernel<<<grid, 256, 0, stream>>>(x, gidx, wt2, bias, out_sel, out_idx,
                                                 fix_cnt, fix_list, fix_cap);
    fixup_kernel<<<1024, 256, 0, stream>>>(x, gidx, wT, bias, out_sel, out_idx,
                                           fix_cnt, fix_list, fix_cap);
}